// Round 12
// baseline (24.970 us; speedup 1.0000x reference)
//
#include <hip/hip_runtime.h>

#define NN 512
#define DD 9
#define LL 32
#define NT2 16   // 32x32 tiles per dimension
#define PGD 17   // padded group stride (odd -> conflict-free)

typedef _Float16 f16x8  __attribute__((ext_vector_type(8)));
typedef float    f32x16 __attribute__((ext_vector_type(16)));

// One block per batch, 1024 threads = 16 waves. Two sequential passes per wave
// (no barrier needed between: sA/sB are read-only during scans, part arrays
// disjoint). Wave w owns a-tile w (32 rows), scans 16 b-tiles of 32 cols.
// MFMA 32x32x16 f16 emits the complete distance: K = 12 cross slots
// (hh, h*lo, lo*h; lo*lo dropped, |err| ~2e-6) + 4 norm slots.
// Tracking: pk = (dbits & ~15) | jj (and_or), fminf accumulate = 2 VALU/cell.
// C-layout: col = lane&31, row = (reg&3) + 8*(reg>>2) + 4*(lane>>5).
__global__ __launch_bounds__(1024, 4)
void loss_kernel(const float* __restrict__ kine_input,
                 const float* __restrict__ class_input,
                 const float* __restrict__ kine_pred,
                 const float* __restrict__ class_pred,
                 const float* __restrict__ mu,
                 const float* __restrict__ log_var,
                 float* __restrict__ out)
{
    const int b    = (int)blockIdx.x;
    const int t    = (int)threadIdx.x;
    const int lane = t & 63;
    const int wave = t >> 6;

    __shared__ f16x8          sA[NT2 * 64];        // input-side fragments (encA), 16 KB
    __shared__ f16x8          sB[NT2 * 64];        // pred-side fragments (encB), 16 KB
    __shared__ float          part_d[2][NN][PGD];  // per-(row, col-group) min dist, 68 KB
    __shared__ unsigned short part_c[2][NN][PGD];  // matching argmin col, 34 KB
    __shared__ float          red[16];
    __shared__ float          s_kl;
    __shared__ int            hist_in[DD], hist_pr[DD];

    if (t < DD) { hist_in[t] = 0; hist_pr[t] = 0; }

    // ---- hoisted epilogue operand: own class row ----
    const int ep_p  = t >> 9;
    const int ep_lr = t & (NN - 1);
    const float* own = (ep_p ? class_pred : class_input) + ((size_t)b * NN + ep_lr) * DD;
    float ownv[DD];
    #pragma unroll
    for (int d2 = 0; d2 < DD; ++d2) ownv[d2] = own[d2];

    // ---- stage fragments: thread stages slot (side=rep, tile=wave, lane) ----
    // A/B lane layout: point index = lane&31, k = (lane>>5)*8 + e.
    // Slot plan (c = k&3): k0-3 A=hi B=hi, k4-7 A=hi B=lo, k8-11 A=lo B=hi,
    // k12..15 norms: (A,B) = (1,y2hi),(1,y2lo),(x2hi,1),(x2lo,1).
    // encA half0 = [hi0..3, hi0..3], half1 = [lo0..3, 1, 1, x2hi, x2lo]
    // encB half0 = [hi0..3, lo0..3], half1 = [hi0..3, y2hi, y2lo, 1, 1]
    #pragma unroll
    for (int rep = 0; rep < 2; ++rep) {
        const int side = rep;
        const int row  = wave * 32 + (lane & 31);
        const int half = lane >> 5;
        const float* P = side ? kine_pred : kine_input;
        float4 pt = *reinterpret_cast<const float4*>(P + ((size_t)b * NN + row) * 4);
        float n = pt.x*pt.x + pt.y*pt.y + pt.z*pt.z + pt.w*pt.w;
        float w[4];
        if (side == 0) { w[0] = -2.f*pt.x; w[1] = -2.f*pt.y; w[2] = -2.f*pt.z; w[3] = -2.f*pt.w; }
        else           { w[0] =      pt.x; w[1] =      pt.y; w[2] =      pt.z; w[3] =      pt.w; }
        _Float16 hi[4], lo[4];
        #pragma unroll
        for (int c = 0; c < 4; ++c) { hi[c] = (_Float16)w[c]; lo[c] = (_Float16)(w[c] - (float)hi[c]); }
        const _Float16 nhi = (_Float16)n;
        const _Float16 nlo = (_Float16)(n - (float)nhi);
        const _Float16 one = (_Float16)1.f;
        f16x8 hv;
        if (side == 0) {
            if (half == 0) { hv[0]=hi[0]; hv[1]=hi[1]; hv[2]=hi[2]; hv[3]=hi[3];
                             hv[4]=hi[0]; hv[5]=hi[1]; hv[6]=hi[2]; hv[7]=hi[3]; }
            else           { hv[0]=lo[0]; hv[1]=lo[1]; hv[2]=lo[2]; hv[3]=lo[3];
                             hv[4]=one;   hv[5]=one;   hv[6]=nhi;   hv[7]=nlo; }
        } else {
            if (half == 0) { hv[0]=hi[0]; hv[1]=hi[1]; hv[2]=hi[2]; hv[3]=hi[3];
                             hv[4]=lo[0]; hv[5]=lo[1]; hv[6]=lo[2]; hv[7]=lo[3]; }
            else           { hv[0]=hi[0]; hv[1]=hi[1]; hv[2]=hi[2]; hv[3]=hi[3];
                             hv[4]=nhi;   hv[5]=nlo;   hv[6]=one;   hv[7]=one; }
        }
        (side ? sB : sA)[wave * 64 + lane] = hv;
    }
    __syncthreads();

    // ---- two sequential scan passes (p=0: input rows; p=1: pred rows) ----
    const f32x16 zero16 = {0.f,0.f,0.f,0.f,0.f,0.f,0.f,0.f,
                           0.f,0.f,0.f,0.f,0.f,0.f,0.f,0.f};
    #pragma unroll
    for (int p = 0; p < 2; ++p) {
        const f16x8* arrA = p ? sB : sA;
        const f16x8* arrB = p ? sA : sB;
        const f16x8  afr  = arrA[wave * 64 + lane];

        float bm[16];
        #pragma unroll
        for (int i = 0; i < 16; ++i) bm[i] = 1e30f;

        f16x8 bfr = arrB[lane];   // prefetch jj=0
        #pragma unroll 2
        for (int jj = 0; jj < NT2; ++jj) {
            f16x8 cur = bfr;
            if (jj < NT2 - 1) bfr = arrB[(jj + 1) * 64 + lane];
            f32x16 dd = __builtin_amdgcn_mfma_f32_32x32x16_f16(afr, cur, zero16, 0, 0, 0);
            #pragma unroll
            for (int r = 0; r < 16; ++r) {
                unsigned pk = (__float_as_uint(dd[r]) & 0xFFFFFFF0u) | (unsigned)jj;
                bm[r] = fminf(bm[r], __uint_as_float(pk));
            }
        }

        // xor-16 lex merge (col groups c and c+16), then write (d, col) partials
        const int rowbase = wave * 32 + 4 * (lane >> 5);
        #pragma unroll
        for (int r = 0; r < 16; ++r) {
            unsigned pk  = __float_as_uint(bm[r]);
            float    dp  = __uint_as_float(pk & 0xFFFFFFF0u);
            unsigned col = (unsigned)(lane & 31) | ((pk & 15u) << 5);
            float    qd  = __shfl_xor(dp, 16, 64);
            unsigned qc  = (unsigned)__shfl_xor((int)col, 16, 64);
            bool take = (qd < dp) || (qd == dp && qc < col);
            dp  = take ? qd : dp;
            col = take ? qc : col;
            if ((lane & 16) == 0) {
                const int row = rowbase + (r & 3) + 8 * (r >> 2);
                part_d[p][row][lane & 15] = dp;
                part_c[p][row][lane & 15] = (unsigned short)col;
            }
        }
    }

    // ---- histograms (labels independent of argmins) + KL ----
    {
        const float* cls = (t < NN) ? class_input : class_pred;
        const int r = t & (NN - 1);
        const float* rowp = cls + ((size_t)b * NN + r) * DD;
        float mx = rowp[0]; int lab = 0;
        #pragma unroll
        for (int d2 = 1; d2 < DD; ++d2) { float v = rowp[d2]; if (v > mx) { mx = v; lab = d2; } }  // argmax(exp)==argmax
        atomicAdd((t < NN) ? &hist_in[lab] : &hist_pr[lab], 1);
    }
    if (t < 64) {
        float v = 0.f;
        if (t < LL) {
            float m_ = mu[(size_t)b * LL + t];
            float lv = log_var[(size_t)b * LL + t];
            v = 1.f + lv - m_ * m_ - expf(lv);
        }
        #pragma unroll
        for (int off = 32; off > 0; off >>= 1) v += __shfl_down(v, off, 64);
        if (t == 0) s_kl = -0.5f * v;
    }
    __syncthreads();

    // ---- epilogue: thread t -> (pass ep_p, row ep_lr); lex-merge 16 groups ----
    float partsum;
    {
        float    bd = part_d[ep_p][ep_lr][0];
        unsigned bc = part_c[ep_p][ep_lr][0];
        #pragma unroll
        for (int g = 1; g < 16; ++g) {
            float    d = part_d[ep_p][ep_lr][g];
            unsigned c = part_c[ep_p][ep_lr][g];
            if (d < bd || (d == bd && c < bc)) { bd = d; bc = c; }
        }
        const float dmin = fmaxf(bd, 0.f);   // clamp commutes with min (ref semantics)
        const int   idx  = (int)bc;
        const float* oth = (ep_p ? class_input : class_pred) + ((size_t)b * NN + idx) * DD;
        float dot = 0.f;
        #pragma unroll
        for (int d2 = 0; d2 < DD; ++d2) dot += ownv[d2] * oth[d2];
        partsum = dmin - dot;   // chamfer + (-1)*class dot (W=1)
    }
    #pragma unroll
    for (int off = 32; off > 0; off >>= 1) partsum += __shfl_down(partsum, off, 64);
    if (lane == 0) red[wave] = partsum;
    __syncthreads();

    if (t == 0) {
        float sum = 0.f;
        #pragma unroll
        for (int w2 = 0; w2 < 16; ++w2) sum += red[w2];
        float cnum = 0.f;
        #pragma unroll
        for (int c = 0; c < DD; ++c) {
            float diff = fabsf((float)(hist_pr[c] - hist_in[c]));
            float wgt = (c == 0) ? 2.0f : ((c == DD - 1) ? 100.0f : 1.0f);
            cnum += wgt * diff;
        }
        out[b] = 0.99f * (sum + 0.001f * cnum) + 0.01f * s_kl;
    }
}

extern "C" void kernel_launch(void* const* d_in, const int* in_sizes, int n_in,
                              void* d_out, int out_size, void* d_ws, size_t ws_size,
                              hipStream_t stream) {
    const float* kine_input  = (const float*)d_in[0];
    const float* class_input = (const float*)d_in[1];
    const float* kine_pred   = (const float*)d_in[2];
    const float* class_pred  = (const float*)d_in[3];
    const float* mu          = (const float*)d_in[4];
    const float* log_var     = (const float*)d_in[5];
    float* out = (float*)d_out;

    loss_kernel<<<256, 1024, 0, stream>>>(kine_input, class_input, kine_pred,
                                          class_pred, mu, log_var, out);
}